// Round 8
// baseline (2141.800 us; speedup 1.0000x reference)
//
#include <hip/hip_runtime.h>

#define N_NODES 100000
#define D_FEAT  64
#define N_EDGES 3200000
#define GAMMA   0.5f

#define BSH   7                                   // 128 nodes per bucket
#define BN    (1 << BSH)                          // 128
#define NB    ((N_NODES + BN - 1) >> BSH)         // 782 buckets
#define TSTRIDE 65                                // padded tile row (floats)

#define H_BLOCKS 1024
#define H_EPB    ((N_EDGES + H_BLOCKS - 1) / H_BLOCKS)   // 3125

#define CVT_V4     (N_NODES * D_FEAT / 4)         // 1,600,000 float4
#define CVT_BLOCKS ((CVT_V4 + 255) / 256)         // 6250

#define SRC_MASK 0x1FFFFu                         // 17 bits for src

// ---- P0: fused [dst-bucket histogram + zero edge-out] | [h f32->bf16] ----
__global__ void pre_kernel(const float* __restrict__ h,
                           const int* __restrict__ dst,
                           unsigned short* __restrict__ h16,
                           int* __restrict__ counts,
                           float* __restrict__ out_edge) {
    __shared__ int lcnt[NB];
    const int bid = blockIdx.x;
    if (bid < H_BLOCKS) {
        for (int i = threadIdx.x; i < NB; i += 256) lcnt[i] = 0;
        __syncthreads();
        int base = bid * H_EPB;
        int end  = base + H_EPB; if (end > N_EDGES) end = N_EDGES;
        for (int i = base + threadIdx.x; i < end; i += 256) {
            __hip_atomic_fetch_add(&lcnt[dst[i] >> BSH], 1,
                                   __ATOMIC_RELAXED, __HIP_MEMORY_SCOPE_WORKGROUP);
            out_edge[i] = 0.0f;
        }
        __syncthreads();
        for (int i = threadIdx.x; i < NB; i += 256) {
            int c = lcnt[i];
            if (c) atomicAdd(&counts[i], c);
        }
    } else {
        int i = (bid - H_BLOCKS) * 256 + threadIdx.x;
        if (i < CVT_V4) {
            float4 v = ((const float4*)h)[i];
            ushort4 o;
            unsigned u;
            u = __float_as_uint(v.x); o.x = (unsigned short)((u + 0x7fffu + ((u >> 16) & 1u)) >> 16);
            u = __float_as_uint(v.y); o.y = (unsigned short)((u + 0x7fffu + ((u >> 16) & 1u)) >> 16);
            u = __float_as_uint(v.z); o.z = (unsigned short)((u + 0x7fffu + ((u >> 16) & 1u)) >> 16);
            u = __float_as_uint(v.w); o.w = (unsigned short)((u + 0x7fffu + ((u >> 16) & 1u)) >> 16);
            ((ushort4*)h16)[i] = o;
        }
    }
}

// ---- P1: scan 782 bucket counts -> offs/curs (1 block, 512 thr, 2/thread) ----
__global__ void scan_kernel(const int* __restrict__ counts,
                            int* __restrict__ offs,
                            int* __restrict__ curs) {
    __shared__ int ps[512];
    const int t  = threadIdx.x;
    const int i0 = 2 * t, i1 = 2 * t + 1;
    int a  = (i0 < NB) ? counts[i0] : 0;
    int c1 = (i1 < NB) ? counts[i1] : 0;
    ps[t] = a + c1;
    __syncthreads();
    for (int off = 1; off < 512; off <<= 1) {
        int v = 0;
        if (t >= off) v = ps[t - off];
        __syncthreads();
        ps[t] += v;
        __syncthreads();
    }
    int incl = ps[t];
    int excl = incl - (a + c1);
    if (i0 < NB) { offs[i0] = excl;     curs[i0] = excl; }
    if (i1 < NB) { offs[i1] = excl + a; curs[i1] = excl + a; }
    if (t == 511) offs[NB] = incl;                 // == N_EDGES
}

// ---- K1': direct scatter. 782 hot cursors => writes cluster near each
// bucket's cursor (line-filling, no write amplification). No LDS, no barriers.
__global__ void __launch_bounds__(256)
scatter_direct_kernel(const int* __restrict__ src,
                      const int* __restrict__ dst,
                      const float* __restrict__ e,
                      int* __restrict__ curs,
                      uint2* __restrict__ recs) {
    int i = blockIdx.x * 256 + threadIdx.x;
    if (i >= N_EDGES) return;
    int t = dst[i];
    int b = t >> BSH;
    int p = atomicAdd(&curs[b], 1);
    unsigned pk = (unsigned)src[i] | ((unsigned)(t & (BN - 1)) << 17);
    recs[p] = make_uint2(pk, __float_as_uint(e[i]));
}

// ---- K4: per-bucket LDS tile accumulate (f32 ds-atomics) + fused epilogue.
// 33 KB LDS -> 4 blocks/CU; 782 blocks ~ 3.05/CU. 8 lanes per rec (uint4 row),
// 64 recs per block-iteration.
__global__ void __launch_bounds__(512)
tile_accum_kernel(const float* __restrict__ h,
                  const unsigned short* __restrict__ h16,
                  const int* __restrict__ offs,
                  const uint2* __restrict__ recs,
                  float* __restrict__ out) {
    __shared__ float tile[BN * TSTRIDE];          // 33280 B
    const int b   = blockIdx.x;
    const int t   = threadIdx.x;
    const int g   = t >> 3;                       // rec group 0..63
    const int sub = t & 7;                        // uint4 slot 0..7

    for (int i = t; i < BN * TSTRIDE; i += 512) tile[i] = 0.0f;
    __syncthreads();

    const int lo = offs[b], hi = offs[b + 1];
    const uint4* __restrict__ hv = (const uint4*)h16;

#define ACC_REC(r)                                                           \
    {                                                                        \
        uint4 v = hv[((r).x & SRC_MASK) * 8 + sub];                          \
        float w = __uint_as_float((r).y);                                    \
        int bi = (int)((r).x >> 17) * TSTRIDE + sub * 8;                     \
        __hip_atomic_fetch_add(&tile[bi + 0], __uint_as_float(v.x << 16) * w,          __ATOMIC_RELAXED, __HIP_MEMORY_SCOPE_WORKGROUP); \
        __hip_atomic_fetch_add(&tile[bi + 1], __uint_as_float(v.x & 0xFFFF0000u) * w,  __ATOMIC_RELAXED, __HIP_MEMORY_SCOPE_WORKGROUP); \
        __hip_atomic_fetch_add(&tile[bi + 2], __uint_as_float(v.y << 16) * w,          __ATOMIC_RELAXED, __HIP_MEMORY_SCOPE_WORKGROUP); \
        __hip_atomic_fetch_add(&tile[bi + 3], __uint_as_float(v.y & 0xFFFF0000u) * w,  __ATOMIC_RELAXED, __HIP_MEMORY_SCOPE_WORKGROUP); \
        __hip_atomic_fetch_add(&tile[bi + 4], __uint_as_float(v.z << 16) * w,          __ATOMIC_RELAXED, __HIP_MEMORY_SCOPE_WORKGROUP); \
        __hip_atomic_fetch_add(&tile[bi + 5], __uint_as_float(v.z & 0xFFFF0000u) * w,  __ATOMIC_RELAXED, __HIP_MEMORY_SCOPE_WORKGROUP); \
        __hip_atomic_fetch_add(&tile[bi + 6], __uint_as_float(v.w << 16) * w,          __ATOMIC_RELAXED, __HIP_MEMORY_SCOPE_WORKGROUP); \
        __hip_atomic_fetch_add(&tile[bi + 7], __uint_as_float(v.w & 0xFFFF0000u) * w,  __ATOMIC_RELAXED, __HIP_MEMORY_SCOPE_WORKGROUP); \
    }

    int kk = lo + g;
    while (kk < hi) {
        uint2 r0 = recs[kk];
        // padded second rec: key 0 / weight 0 -> adds 0.0f, harmless
        uint2 r1 = (kk + 64 < hi) ? recs[kk + 64] : make_uint2(0u, 0u);
        ACC_REC(r0);
        ACC_REC(r1);
        kk += 128;
    }
#undef ACC_REC
    __syncthreads();

    // epilogue: tile -> out, fused -GAMMA*h0 (f32)
    const int nbase = b << BSH;
    int nmax = N_NODES - nbase; if (nmax > BN) nmax = BN;
    const float4* __restrict__ h4 = (const float4*)h;
    float4*       __restrict__ o4 = (float4*)out;
    for (int i = t; i < nmax * 16; i += 512) {
        int nl = i >> 4, k = i & 15;
        int ti = nl * TSTRIDE + k * 4;
        int o  = (nbase + nl) * 16 + k;
        float4 p = h4[o];
        float4 r;
        r.x = tile[ti + 0] - GAMMA * p.x;
        r.y = tile[ti + 1] - GAMMA * p.y;
        r.z = tile[ti + 2] - GAMMA * p.z;
        r.w = tile[ti + 3] - GAMMA * p.w;
        o4[o] = r;
    }
}

// ---------------- fallback atomic path (if ws too small) ----------------
__global__ void init_out_kernel(const float* __restrict__ x,
                                float* __restrict__ out,
                                int nd, int total) {
    int i = blockIdx.x * blockDim.x + threadIdx.x;
    if (i < nd)         out[i] = -GAMMA * x[i];
    else if (i < total) out[i] = 0.0f;
}

__global__ void edge_scatter_kernel(const float* __restrict__ h,
                                    const float* __restrict__ e,
                                    const int* __restrict__ src,
                                    const int* __restrict__ dst,
                                    float* __restrict__ out) {
    long long idx = (long long)blockIdx.x * blockDim.x + threadIdx.x;
    int edge = (int)(idx >> 6);
    int d    = (int)(idx & 63);
    if (edge >= N_EDGES) return;
    atomicAdd(&out[dst[edge] * D_FEAT + d], h[src[edge] * D_FEAT + d] * e[edge]);
}

// ---------------- launch ----------------
extern "C" void kernel_launch(void* const* d_in, const int* in_sizes, int n_in,
                              void* d_out, int out_size, void* d_ws, size_t ws_size,
                              hipStream_t stream) {
    const float* x   = (const float*)d_in[1];
    const int*   src = (const int*)d_in[2];
    const int*   dst = (const int*)d_in[3];
    float*       out = (float*)d_out;

    const int nd = N_NODES * D_FEAT;

    // ws: counts[NB] | offs[NB+1] | curs[NB] | pad | recs[E] (uint2) | h16[nd]
    size_t ints    = (size_t)NB * 3 + 1;
    size_t rec_off = (ints * 4 + 15) & ~(size_t)15;
    size_t h16_off = rec_off + (size_t)N_EDGES * 8;
    size_t needed  = h16_off + (size_t)nd * 2;

    if (ws_size >= needed) {
        int*   counts = (int*)d_ws;
        int*   offs   = counts + NB;
        int*   curs   = offs + NB + 1;
        uint2* recs   = (uint2*)((char*)d_ws + rec_off);
        unsigned short* h16 = (unsigned short*)((char*)d_ws + h16_off);

        hipMemsetAsync(counts, 0, NB * sizeof(int), stream);
        pre_kernel<<<H_BLOCKS + CVT_BLOCKS, 256, 0, stream>>>(x, dst, h16, counts, out + nd);
        scan_kernel<<<1, 512, 0, stream>>>(counts, offs, curs);
        scatter_direct_kernel<<<(N_EDGES + 255) / 256, 256, 0, stream>>>(
            src, dst, x + nd, curs, recs);
        tile_accum_kernel<<<NB, 512, 0, stream>>>(x, h16, offs, recs, out);
    } else {
        const int total = nd + N_EDGES;
        init_out_kernel<<<(total + 255) / 256, 256, 0, stream>>>(x, out, nd, total);
        long long threads = (long long)N_EDGES * 64;
        edge_scatter_kernel<<<(int)((threads + 255) / 256), 256, 0, stream>>>(
            x, x + nd, src, dst, out);
    }
}

// Round 9
// 220.260 us; speedup vs baseline: 9.7240x; 9.7240x over previous
//
#include <hip/hip_runtime.h>

#define N_NODES 100000
#define D_FEAT  64
#define N_EDGES 3200000
#define GAMMA   0.5f

#define BSH   7                                   // 128 nodes per bucket
#define BN    (1 << BSH)                          // 128
#define NB    ((N_NODES + BN - 1) >> BSH)         // 782 buckets

#define H_BLOCKS 1024
#define H_EPB    ((N_EDGES + H_BLOCKS - 1) / H_BLOCKS)   // 3125

#define CVT_V4     (N_NODES * D_FEAT / 4)         // 1,600,000 float4
#define CVT_BLOCKS ((CVT_V4 + 255) / 256)         // 6250

#define K1_CH    4096                             // edges per K1 block
#define K1_BLOCKS ((N_EDGES + K1_CH - 1) / K1_CH) // 782

#define K2_CAP   4736                             // bucket cap (avg 4092, +10 sigma)

#define SRC_MASK 0x1FFFFu                         // 17 bits for src

// ---- P0: fused [dst-bucket histogram + zero edge-out] | [h f32->bf16] ----
__global__ void pre_kernel(const float* __restrict__ h,
                           const int* __restrict__ dst,
                           unsigned short* __restrict__ h16,
                           int* __restrict__ counts,
                           float* __restrict__ out_edge) {
    __shared__ int lcnt[NB];
    const int bid = blockIdx.x;
    if (bid < H_BLOCKS) {
        for (int i = threadIdx.x; i < NB; i += 256) lcnt[i] = 0;
        __syncthreads();
        int base = bid * H_EPB;
        int end  = base + H_EPB; if (end > N_EDGES) end = N_EDGES;
        for (int i = base + threadIdx.x; i < end; i += 256) {
            __hip_atomic_fetch_add(&lcnt[dst[i] >> BSH], 1,
                                   __ATOMIC_RELAXED, __HIP_MEMORY_SCOPE_WORKGROUP);
            out_edge[i] = 0.0f;
        }
        __syncthreads();
        for (int i = threadIdx.x; i < NB; i += 256) {
            int c = lcnt[i];
            if (c) atomicAdd(&counts[i], c);
        }
    } else {
        int i = (bid - H_BLOCKS) * 256 + threadIdx.x;
        if (i < CVT_V4) {
            float4 v = ((const float4*)h)[i];
            ushort4 o;
            unsigned u;
            u = __float_as_uint(v.x); o.x = (unsigned short)((u + 0x7fffu + ((u >> 16) & 1u)) >> 16);
            u = __float_as_uint(v.y); o.y = (unsigned short)((u + 0x7fffu + ((u >> 16) & 1u)) >> 16);
            u = __float_as_uint(v.z); o.z = (unsigned short)((u + 0x7fffu + ((u >> 16) & 1u)) >> 16);
            u = __float_as_uint(v.w); o.w = (unsigned short)((u + 0x7fffu + ((u >> 16) & 1u)) >> 16);
            ((ushort4*)h16)[i] = o;
        }
    }
}

// ---- P1: scan 782 bucket counts (2/thread) -> offs/curs; init bflag ----
__global__ void scan_kernel(const int* __restrict__ counts,
                            int* __restrict__ offs,
                            int* __restrict__ curs,
                            int* __restrict__ bflag,
                            int* __restrict__ node_offs) {
    __shared__ int ps[512];
    const int t  = threadIdx.x;
    const int i0 = 2 * t, i1 = 2 * t + 1;
    int a  = (i0 < NB) ? counts[i0] : 0;
    int c1 = (i1 < NB) ? counts[i1] : 0;
    ps[t] = a + c1;
    __syncthreads();
    for (int off = 1; off < 512; off <<= 1) {
        int v = 0;
        if (t >= off) v = ps[t - off];
        __syncthreads();
        ps[t] += v;
        __syncthreads();
    }
    int incl = ps[t];
    int excl = incl - (a + c1);
    if (i0 < NB) { offs[i0] = excl;     curs[i0] = excl;     bflag[i0] = 0; }
    if (i1 < NB) { offs[i1] = excl + a; curs[i1] = excl + a; bflag[i1] = 0; }
    if (t == 511) offs[NB] = incl;                 // == N_EDGES
    if (t == 0) node_offs[N_NODES] = N_EDGES;
}

// ---- K1: chunk-local LDS sort by bucket, burst-copy to global bins ----
__global__ void __launch_bounds__(512)
bucket_scatter_kernel(const int* __restrict__ src,
                      const int* __restrict__ dst,
                      const float* __restrict__ e,
                      int* __restrict__ curs,
                      uint2* __restrict__ recs) {
    __shared__ uint2          stage[K1_CH];       // 32 KB
    __shared__ unsigned short bkt16[K1_CH];       // 8 KB
    __shared__ int hist[NB], ebuf[NB], cur[NB], gbase[NB];  // 12.5 KB
    __shared__ int ps[512];                       // 2 KB

    const int t    = threadIdx.x;
    const int base = blockIdx.x * K1_CH;
    int chcnt = N_EDGES - base; if (chcnt > K1_CH) chcnt = K1_CH;

    int dv[8];                                    // register-cached dst
    for (int i = t; i < NB; i += 512) hist[i] = 0;
    __syncthreads();
#pragma unroll
    for (int j = 0; j < 8; ++j) {
        int i = j * 512 + t;
        if (i < chcnt) {
            dv[j] = dst[base + i];
            __hip_atomic_fetch_add(&hist[dv[j] >> BSH], 1,
                                   __ATOMIC_RELAXED, __HIP_MEMORY_SCOPE_WORKGROUP);
        } else dv[j] = -1;
    }
    __syncthreads();
    // scan 782 bins, 2 per thread
    const int i0 = 2 * t, i1 = 2 * t + 1;
    int a  = (i0 < NB) ? hist[i0] : 0;
    int c1 = (i1 < NB) ? hist[i1] : 0;
    ps[t] = a + c1;
    __syncthreads();
    for (int off = 1; off < 512; off <<= 1) {
        int v = 0;
        if (t >= off) v = ps[t - off];
        __syncthreads();
        ps[t] += v;
        __syncthreads();
    }
    int excl = ps[t] - (a + c1);
    if (i0 < NB) {
        ebuf[i0] = excl; cur[i0] = 0;
        gbase[i0] = a  ? atomicAdd(&curs[i0], a)  : 0;
    }
    if (i1 < NB) {
        ebuf[i1] = excl + a; cur[i1] = 0;
        gbase[i1] = c1 ? atomicAdd(&curs[i1], c1) : 0;
    }
    __syncthreads();
#pragma unroll
    for (int j = 0; j < 8; ++j) {
        int i = j * 512 + t;
        if (dv[j] >= 0) {
            int gi = base + i;
            int b  = dv[j] >> BSH;
            int p  = ebuf[b] + __hip_atomic_fetch_add(&cur[b], 1,
                            __ATOMIC_RELAXED, __HIP_MEMORY_SCOPE_WORKGROUP);
            unsigned pk = (unsigned)src[gi] | ((unsigned)(dv[j] & (BN - 1)) << 17);
            stage[p] = make_uint2(pk, __float_as_uint(e[gi]));
            bkt16[p] = (unsigned short)b;
        }
    }
    __syncthreads();
    for (int i = t; i < chcnt; i += 512) {
        int b = bkt16[i];
        recs[gbase[b] + (i - ebuf[b])] = stage[i];
    }
}

// ---- K2: per-bucket node-level sort (in LDS, in place) + node_offs ----
// 256 threads, ~39.5 KB LDS -> 4 blocks/CU; 782 blocks ~ 3.05/CU balanced.
__global__ void __launch_bounds__(256)
node_sort_kernel(const int* __restrict__ offs,
                 uint2* __restrict__ recs,
                 int* __restrict__ bflag,
                 int* __restrict__ node_offs) {
    __shared__ uint2 buf[K2_CAP];                 // 37888 B
    __shared__ int hist[BN], ebuf[BN], cur[BN];   // 1536 B

    const int b  = blockIdx.x;
    const int t  = threadIdx.x;
    const int lo = offs[b];
    const int cnt = offs[b + 1] - lo;

    if (cnt > K2_CAP) {                           // overflow fallback (rare)
        if (t == 0) bflag[b] = 1;
        if (t < BN) {
            int g = (b << BSH) + t;
            if (g < N_NODES) node_offs[g] = lo;
        }
        return;
    }

    if (t < BN) { hist[t] = 0; cur[t] = 0; }
    __syncthreads();
    for (int i = t; i < cnt; i += 256) {
        uint2 r = recs[lo + i];
        buf[i] = r;
        __hip_atomic_fetch_add(&hist[r.x >> 17], 1,
                               __ATOMIC_RELAXED, __HIP_MEMORY_SCOPE_WORKGROUP);
    }
    __syncthreads();
    int c = 0;
    if (t < BN) { c = hist[t]; ebuf[t] = c; }
    __syncthreads();
    for (int off = 1; off < BN; off <<= 1) {
        int v = 0;
        if (t < BN && t >= off) v = ebuf[t - off];
        __syncthreads();
        if (t < BN) ebuf[t] += v;
        __syncthreads();
    }
    if (t < BN) {
        int exc = ebuf[t] - c;
        ebuf[t] = exc;
        int g = (b << BSH) + t;
        if (g < N_NODES) node_offs[g] = lo + exc;
    }
    __syncthreads();
    for (int i = t; i < cnt; i += 256) {
        uint2 r = buf[i];
        int dl = r.x >> 17;
        int p  = lo + ebuf[dl] + __hip_atomic_fetch_add(&cur[dl], 1,
                        __ATOMIC_RELAXED, __HIP_MEMORY_SCOPE_WORKGROUP);
        recs[p] = r;
    }
}

// ---- K3 (bf16 h): wave = node; 8 groups x 8 lanes; uint4 row loads ----
__global__ void __launch_bounds__(512)
gather_bf16_kernel(const float* __restrict__ h,
                   const unsigned short* __restrict__ h16,
                   const int* __restrict__ offs,
                   const int* __restrict__ node_offs,
                   const int* __restrict__ bflag,
                   const uint2* __restrict__ recs,
                   float* __restrict__ out) {
    const int wid = threadIdx.x >> 6;
    const int n   = blockIdx.x * 8 + wid;
    if (n >= N_NODES) return;
    const int lane = threadIdx.x & 63;
    const int g    = lane >> 3;        // 0..7
    const int sub  = lane & 7;         // 0..7
    const int b    = n >> BSH;

    const uint4* __restrict__ hv = (const uint4*)h16;   // 8 uint4 per row

    float a0=0.f,a1=0.f,a2=0.f,a3=0.f,a4=0.f,a5=0.f,a6=0.f,a7=0.f;

#define ACC_REC(r)                                                          \
    {                                                                       \
        uint4 v = hv[(r.x & SRC_MASK) * 8 + sub];                           \
        float w = __uint_as_float(r.y);                                     \
        a0 += __uint_as_float(v.x << 16) * w;                               \
        a1 += __uint_as_float(v.x & 0xFFFF0000u) * w;                       \
        a2 += __uint_as_float(v.y << 16) * w;                               \
        a3 += __uint_as_float(v.y & 0xFFFF0000u) * w;                       \
        a4 += __uint_as_float(v.z << 16) * w;                               \
        a5 += __uint_as_float(v.z & 0xFFFF0000u) * w;                       \
        a6 += __uint_as_float(v.w << 16) * w;                               \
        a7 += __uint_as_float(v.w & 0xFFFF0000u) * w;                       \
    }

    if (!bflag[b]) {
        const int lo = node_offs[n], hi = node_offs[n + 1];
        int kk = lo + g;
        while (kk < hi) {
            uint2 r0 = recs[kk];
            uint2 r1 = (kk +  8 < hi) ? recs[kk +  8] : make_uint2(0u, 0u);
            uint2 r2 = (kk + 16 < hi) ? recs[kk + 16] : make_uint2(0u, 0u);
            uint2 r3 = (kk + 24 < hi) ? recs[kk + 24] : make_uint2(0u, 0u);
            ACC_REC(r0); ACC_REC(r1); ACC_REC(r2); ACC_REC(r3);
            kk += 32;
        }
    } else {                                      // unsorted bucket: scan-match
        const int lo = offs[b], hi = offs[b + 1];
        const unsigned dl = (unsigned)(n & (BN - 1));
        for (int k = lo + g; k < hi; k += 8) {
            uint2 r = recs[k];
            if ((r.x >> 17) == dl) ACC_REC(r);
        }
    }
#undef ACC_REC

    for (int m = 8; m <= 32; m <<= 1) {
        a0 += __shfl_xor(a0, m); a1 += __shfl_xor(a1, m);
        a2 += __shfl_xor(a2, m); a3 += __shfl_xor(a3, m);
        a4 += __shfl_xor(a4, m); a5 += __shfl_xor(a5, m);
        a6 += __shfl_xor(a6, m); a7 += __shfl_xor(a7, m);
    }

    if (g == 0) {
        const float4* __restrict__ h4 = (const float4*)h;
        const int o = n * 16 + sub * 2;
        float4 p = h4[o], q = h4[o + 1];
        float4 r0, r1;
        r0.x = a0 - GAMMA * p.x; r0.y = a1 - GAMMA * p.y;
        r0.z = a2 - GAMMA * p.z; r0.w = a3 - GAMMA * p.w;
        r1.x = a4 - GAMMA * q.x; r1.y = a5 - GAMMA * q.y;
        r1.z = a6 - GAMMA * q.z; r1.w = a7 - GAMMA * q.w;
        ((float4*)out)[o]     = r0;
        ((float4*)out)[o + 1] = r1;
    }
}

// ---------------- fallback atomic path (if ws too small) ----------------
__global__ void init_out_kernel(const float* __restrict__ x,
                                float* __restrict__ out,
                                int nd, int total) {
    int i = blockIdx.x * blockDim.x + threadIdx.x;
    if (i < nd)         out[i] = -GAMMA * x[i];
    else if (i < total) out[i] = 0.0f;
}

__global__ void edge_scatter_kernel(const float* __restrict__ h,
                                    const float* __restrict__ e,
                                    const int* __restrict__ src,
                                    const int* __restrict__ dst,
                                    float* __restrict__ out) {
    long long idx = (long long)blockIdx.x * blockDim.x + threadIdx.x;
    int edge = (int)(idx >> 6);
    int d    = (int)(idx & 63);
    if (edge >= N_EDGES) return;
    atomicAdd(&out[dst[edge] * D_FEAT + d], h[src[edge] * D_FEAT + d] * e[edge]);
}

// ---------------- launch ----------------
extern "C" void kernel_launch(void* const* d_in, const int* in_sizes, int n_in,
                              void* d_out, int out_size, void* d_ws, size_t ws_size,
                              hipStream_t stream) {
    const float* x   = (const float*)d_in[1];
    const int*   src = (const int*)d_in[2];
    const int*   dst = (const int*)d_in[3];
    float*       out = (float*)d_out;

    const int nd = N_NODES * D_FEAT;

    // ws: counts[NB] | offs[NB+1] | curs[NB] | bflag[NB] | node_offs[N+1] |
    //     pad | recs[E] (uint2) | h16[nd]
    size_t ints    = (size_t)NB * 4 + 1 + (size_t)N_NODES + 1;
    size_t rec_off = (ints * 4 + 15) & ~(size_t)15;
    size_t h16_off = rec_off + (size_t)N_EDGES * 8;
    size_t needed  = h16_off + (size_t)nd * 2;

    if (ws_size >= needed) {
        int*   counts    = (int*)d_ws;
        int*   offs      = counts + NB;
        int*   curs      = offs + NB + 1;
        int*   bflag     = curs + NB;
        int*   node_offs = bflag + NB;
        uint2* recs      = (uint2*)((char*)d_ws + rec_off);
        unsigned short* h16 = (unsigned short*)((char*)d_ws + h16_off);

        hipMemsetAsync(counts, 0, NB * sizeof(int), stream);
        pre_kernel<<<H_BLOCKS + CVT_BLOCKS, 256, 0, stream>>>(x, dst, h16, counts, out + nd);
        scan_kernel<<<1, 512, 0, stream>>>(counts, offs, curs, bflag, node_offs);
        bucket_scatter_kernel<<<K1_BLOCKS, 512, 0, stream>>>(src, dst, x + nd, curs, recs);
        node_sort_kernel<<<NB, 256, 0, stream>>>(offs, recs, bflag, node_offs);
        gather_bf16_kernel<<<(N_NODES + 7) / 8, 512, 0, stream>>>(
            x, h16, offs, node_offs, bflag, recs, out);
    } else {
        const int total = nd + N_EDGES;
        init_out_kernel<<<(total + 255) / 256, 256, 0, stream>>>(x, out, nd, total);
        long long threads = (long long)N_EDGES * 64;
        edge_scatter_kernel<<<(int)((threads + 255) / 256), 256, 0, stream>>>(
            x, x + nd, src, dst, out);
    }
}

// Round 10
// 179.030 us; speedup vs baseline: 11.9634x; 1.2303x over previous
//
#include <hip/hip_runtime.h>

#define N_NODES 100000
#define D_FEAT  64
#define N_EDGES 3200000
#define GAMMA   0.5f

#define BSH   8                                   // 256 nodes per bucket
#define BN    (1 << BSH)                          // 256
#define NB    ((N_NODES + BN - 1) >> BSH)         // 391 buckets
#define NBP   512                                 // pow2 pad for scans

#define H_BLOCKS 1024
#define H_EPB    ((N_EDGES + H_BLOCKS - 1) / H_BLOCKS)   // 3125

#define CVT_V4     (N_NODES * D_FEAT / 4)         // 1,600,000 float4
#define CVT_BLOCKS ((CVT_V4 + 255) / 256)         // 6250

#define K1_CH    4096                             // edges per K1 block
#define K1_BLOCKS ((N_EDGES + K1_CH - 1) / K1_CH) // 782

#define K2_CAP   10240                            // max recs sortable in LDS

#define SRC_MASK 0x1FFFFu                         // 17 bits for src

// ---- P0: fused [dst-bucket histogram + zero edge-out] | [h f32->bf16] ----
__global__ void pre_kernel(const float* __restrict__ h,
                           const int* __restrict__ dst,
                           unsigned short* __restrict__ h16,
                           int* __restrict__ counts,
                           float* __restrict__ out_edge) {
    __shared__ int lcnt[NB];
    const int bid = blockIdx.x;
    if (bid < H_BLOCKS) {
        for (int i = threadIdx.x; i < NB; i += 256) lcnt[i] = 0;
        __syncthreads();
        int base = bid * H_EPB;
        int end  = base + H_EPB; if (end > N_EDGES) end = N_EDGES;
        for (int i = base + threadIdx.x; i < end; i += 256) {
            __hip_atomic_fetch_add(&lcnt[dst[i] >> BSH], 1,
                                   __ATOMIC_RELAXED, __HIP_MEMORY_SCOPE_WORKGROUP);
            out_edge[i] = 0.0f;
        }
        __syncthreads();
        for (int i = threadIdx.x; i < NB; i += 256) {
            int c = lcnt[i];
            if (c) atomicAdd(&counts[i], c);
        }
    } else {
        int i = (bid - H_BLOCKS) * 256 + threadIdx.x;
        if (i < CVT_V4) {
            float4 v = ((const float4*)h)[i];
            ushort4 o;
            unsigned u;
            u = __float_as_uint(v.x); o.x = (unsigned short)((u + 0x7fffu + ((u >> 16) & 1u)) >> 16);
            u = __float_as_uint(v.y); o.y = (unsigned short)((u + 0x7fffu + ((u >> 16) & 1u)) >> 16);
            u = __float_as_uint(v.z); o.z = (unsigned short)((u + 0x7fffu + ((u >> 16) & 1u)) >> 16);
            u = __float_as_uint(v.w); o.w = (unsigned short)((u + 0x7fffu + ((u >> 16) & 1u)) >> 16);
            ((ushort4*)h16)[i] = o;
        }
    }
}

// ---- P1: scan 391 bucket counts -> offs/curs; init bflag, node_offs tail ----
__global__ void scan_kernel(const int* __restrict__ counts,
                            int* __restrict__ offs,
                            int* __restrict__ curs,
                            int* __restrict__ bflag,
                            int* __restrict__ node_offs) {
    __shared__ int sb[NBP];
    int t = threadIdx.x;
    int c = (t < NB) ? counts[t] : 0;
    sb[t] = c;
    __syncthreads();
    for (int off = 1; off < NBP; off <<= 1) {
        int v = 0;
        if (t >= off) v = sb[t - off];
        __syncthreads();
        sb[t] += v;
        __syncthreads();
    }
    if (t < NB) {
        offs[t] = sb[t] - c;
        curs[t] = sb[t] - c;
        bflag[t] = 0;
    }
    if (t == NBP - 1) offs[NB] = sb[t];
    if (t == 0) node_offs[N_NODES] = N_EDGES;
}

// ---- K1: chunk-local LDS sort by bucket, burst-copy to global bins ----
__global__ void __launch_bounds__(512)
bucket_scatter_kernel(const int* __restrict__ src,
                      const int* __restrict__ dst,
                      const float* __restrict__ e,
                      int* __restrict__ curs,
                      uint2* __restrict__ recs) {
    __shared__ uint2          stage[K1_CH];       // 32 KB
    __shared__ unsigned short bkt16[K1_CH];       // 8 KB
    __shared__ int hist[NB], ebuf[NB], cur[NB], gbase[NB];  // 6.3 KB
    __shared__ int sb[NBP];                       // 2 KB

    const int t    = threadIdx.x;
    const int base = blockIdx.x * K1_CH;
    int chcnt = N_EDGES - base; if (chcnt > K1_CH) chcnt = K1_CH;

    int dv[8];                                    // register-cached dst
    for (int i = t; i < NB; i += 512) hist[i] = 0;
    __syncthreads();
#pragma unroll
    for (int j = 0; j < 8; ++j) {
        int i = j * 512 + t;
        if (i < chcnt) {
            dv[j] = dst[base + i];
            __hip_atomic_fetch_add(&hist[dv[j] >> BSH], 1,
                                   __ATOMIC_RELAXED, __HIP_MEMORY_SCOPE_WORKGROUP);
        } else dv[j] = -1;
    }
    __syncthreads();
    int c = (t < NB) ? hist[t] : 0;
    sb[t] = c;
    __syncthreads();
    for (int off = 1; off < NBP; off <<= 1) {
        int v = 0;
        if (t >= off) v = sb[t - off];
        __syncthreads();
        sb[t] += v;
        __syncthreads();
    }
    if (t < NB) {
        ebuf[t] = sb[t] - c;
        cur[t]  = 0;
        gbase[t] = c ? atomicAdd(&curs[t], c) : 0;
    }
    __syncthreads();
#pragma unroll
    for (int j = 0; j < 8; ++j) {
        int i = j * 512 + t;
        if (dv[j] >= 0) {
            int gi = base + i;
            int b  = dv[j] >> BSH;
            int p  = ebuf[b] + __hip_atomic_fetch_add(&cur[b], 1,
                            __ATOMIC_RELAXED, __HIP_MEMORY_SCOPE_WORKGROUP);
            unsigned pk = (unsigned)src[gi] | ((unsigned)(dv[j] & (BN - 1)) << 17);
            stage[p] = make_uint2(pk, __float_as_uint(e[gi]));
            bkt16[p] = (unsigned short)b;
        }
    }
    __syncthreads();
    for (int i = t; i < chcnt; i += 512) {
        int b = bkt16[i];
        recs[gbase[b] + (i - ebuf[b])] = stage[i];
    }
}

// ---- K2: per-bucket node-level sort (in LDS, in place) + node_offs ----
__global__ void __launch_bounds__(512)
node_sort_kernel(const int* __restrict__ offs,
                 uint2* __restrict__ recs,
                 int* __restrict__ bflag,
                 int* __restrict__ node_offs) {
    __shared__ uint2 buf[K2_CAP];                 // 80 KB
    __shared__ int hist[BN], ebuf[BN], cur[BN];

    const int b  = blockIdx.x;
    const int t  = threadIdx.x;
    const int lo = offs[b];
    const int cnt = offs[b + 1] - lo;

    if (cnt > K2_CAP) {                           // overflow fallback (rare)
        if (t == 0) bflag[b] = 1;
        if (t < BN) {
            int g = (b << BSH) + t;
            if (g < N_NODES) node_offs[g] = lo;
        }
        return;
    }

    for (int i = t; i < cnt; i += 512) buf[i] = recs[lo + i];
    if (t < BN) hist[t] = 0;
    __syncthreads();
    for (int i = t; i < cnt; i += 512) {
        int dl = buf[i].x >> 17;
        __hip_atomic_fetch_add(&hist[dl], 1,
                               __ATOMIC_RELAXED, __HIP_MEMORY_SCOPE_WORKGROUP);
    }
    __syncthreads();
    int c = 0;
    if (t < BN) { c = hist[t]; ebuf[t] = c; }
    __syncthreads();
    for (int off = 1; off < BN; off <<= 1) {
        int v = 0;
        if (t < BN && t >= off) v = ebuf[t - off];
        __syncthreads();
        if (t < BN) ebuf[t] += v;
        __syncthreads();
    }
    if (t < BN) {
        int exc = ebuf[t] - c;
        ebuf[t] = exc;
        cur[t]  = 0;
        int g = (b << BSH) + t;
        if (g < N_NODES) node_offs[g] = lo + exc;
    }
    __syncthreads();
    for (int i = t; i < cnt; i += 512) {
        uint2 r = buf[i];
        int dl = r.x >> 17;
        int p  = lo + ebuf[dl] + __hip_atomic_fetch_add(&cur[dl], 1,
                        __ATOMIC_RELAXED, __HIP_MEMORY_SCOPE_WORKGROUP);
        recs[p] = r;
    }
}

// ---- K3 (bf16 h): wave = node; 8 groups x 8 lanes; uint4 row loads ----
__global__ void __launch_bounds__(512)
gather_bf16_kernel(const float* __restrict__ h,
                   const unsigned short* __restrict__ h16,
                   const int* __restrict__ offs,
                   const int* __restrict__ node_offs,
                   const int* __restrict__ bflag,
                   const uint2* __restrict__ recs,
                   float* __restrict__ out) {
    const int wid = threadIdx.x >> 6;
    const int n   = blockIdx.x * 8 + wid;
    if (n >= N_NODES) return;
    const int lane = threadIdx.x & 63;
    const int g    = lane >> 3;        // 0..7
    const int sub  = lane & 7;         // 0..7
    const int b    = n >> BSH;

    const uint4* __restrict__ hv = (const uint4*)h16;   // 8 uint4 per row

    float a0=0.f,a1=0.f,a2=0.f,a3=0.f,a4=0.f,a5=0.f,a6=0.f,a7=0.f;

#define ACC_REC(r)                                                          \
    {                                                                       \
        uint4 v = hv[(r.x & SRC_MASK) * 8 + sub];                           \
        float w = __uint_as_float(r.y);                                     \
        a0 += __uint_as_float(v.x << 16) * w;                               \
        a1 += __uint_as_float(v.x & 0xFFFF0000u) * w;                       \
        a2 += __uint_as_float(v.y << 16) * w;                               \
        a3 += __uint_as_float(v.y & 0xFFFF0000u) * w;                       \
        a4 += __uint_as_float(v.z << 16) * w;                               \
        a5 += __uint_as_float(v.z & 0xFFFF0000u) * w;                       \
        a6 += __uint_as_float(v.w << 16) * w;                               \
        a7 += __uint_as_float(v.w & 0xFFFF0000u) * w;                       \
    }

    if (!bflag[b]) {
        const int lo = node_offs[n], hi = node_offs[n + 1];
        int kk = lo + g;
        while (kk < hi) {
            uint2 r0 = recs[kk];
            uint2 r1 = (kk +  8 < hi) ? recs[kk +  8] : make_uint2(0u, 0u);
            uint2 r2 = (kk + 16 < hi) ? recs[kk + 16] : make_uint2(0u, 0u);
            uint2 r3 = (kk + 24 < hi) ? recs[kk + 24] : make_uint2(0u, 0u);
            ACC_REC(r0); ACC_REC(r1); ACC_REC(r2); ACC_REC(r3);
            kk += 32;
        }
    } else {                                      // unsorted bucket: scan-match
        const int lo = offs[b], hi = offs[b + 1];
        const unsigned dl = (unsigned)(n & (BN - 1));
        for (int k = lo + g; k < hi; k += 8) {
            uint2 r = recs[k];
            if ((r.x >> 17) == dl) ACC_REC(r);
        }
    }
#undef ACC_REC

    for (int m = 8; m <= 32; m <<= 1) {
        a0 += __shfl_xor(a0, m); a1 += __shfl_xor(a1, m);
        a2 += __shfl_xor(a2, m); a3 += __shfl_xor(a3, m);
        a4 += __shfl_xor(a4, m); a5 += __shfl_xor(a5, m);
        a6 += __shfl_xor(a6, m); a7 += __shfl_xor(a7, m);
    }

    if (g == 0) {
        const float4* __restrict__ h4 = (const float4*)h;
        const int o = n * 16 + sub * 2;
        float4 p = h4[o], q = h4[o + 1];
        float4 r0, r1;
        r0.x = a0 - GAMMA * p.x; r0.y = a1 - GAMMA * p.y;
        r0.z = a2 - GAMMA * p.z; r0.w = a3 - GAMMA * p.w;
        r1.x = a4 - GAMMA * q.x; r1.y = a5 - GAMMA * q.y;
        r1.z = a6 - GAMMA * q.z; r1.w = a7 - GAMMA * q.w;
        ((float4*)out)[o]     = r0;
        ((float4*)out)[o + 1] = r1;
    }
}

// ---------------- fallback atomic path (if ws too small) ----------------
__global__ void init_out_kernel(const float* __restrict__ x,
                                float* __restrict__ out,
                                int nd, int total) {
    int i = blockIdx.x * blockDim.x + threadIdx.x;
    if (i < nd)         out[i] = -GAMMA * x[i];
    else if (i < total) out[i] = 0.0f;
}

__global__ void edge_scatter_kernel(const float* __restrict__ h,
                                    const float* __restrict__ e,
                                    const int* __restrict__ src,
                                    const int* __restrict__ dst,
                                    float* __restrict__ out) {
    long long idx = (long long)blockIdx.x * blockDim.x + threadIdx.x;
    int edge = (int)(idx >> 6);
    int d    = (int)(idx & 63);
    if (edge >= N_EDGES) return;
    atomicAdd(&out[dst[edge] * D_FEAT + d], h[src[edge] * D_FEAT + d] * e[edge]);
}

// ---------------- launch ----------------
extern "C" void kernel_launch(void* const* d_in, const int* in_sizes, int n_in,
                              void* d_out, int out_size, void* d_ws, size_t ws_size,
                              hipStream_t stream) {
    const float* x   = (const float*)d_in[1];
    const int*   src = (const int*)d_in[2];
    const int*   dst = (const int*)d_in[3];
    float*       out = (float*)d_out;

    const int nd = N_NODES * D_FEAT;

    // ws: counts[NB] | offs[NB+1] | curs[NB] | bflag[NB] | node_offs[N+1] |
    //     pad->256B | recs[E] (uint2) | pad->256B | h16[nd]  (h16 rows 128B-aligned)
    size_t ints    = (size_t)NB * 4 + 1 + (size_t)N_NODES + 1;
    size_t rec_off = (ints * 4 + 255) & ~(size_t)255;
    size_t h16_off = (rec_off + (size_t)N_EDGES * 8 + 255) & ~(size_t)255;
    size_t needed  = h16_off + (size_t)nd * 2;

    if (ws_size >= needed) {
        int*   counts    = (int*)d_ws;
        int*   offs      = counts + NB;
        int*   curs      = offs + NB + 1;
        int*   bflag     = curs + NB;
        int*   node_offs = bflag + NB;
        uint2* recs      = (uint2*)((char*)d_ws + rec_off);
        unsigned short* h16 = (unsigned short*)((char*)d_ws + h16_off);

        hipMemsetAsync(counts, 0, NB * sizeof(int), stream);
        pre_kernel<<<H_BLOCKS + CVT_BLOCKS, 256, 0, stream>>>(x, dst, h16, counts, out + nd);
        scan_kernel<<<1, NBP, 0, stream>>>(counts, offs, curs, bflag, node_offs);
        bucket_scatter_kernel<<<K1_BLOCKS, 512, 0, stream>>>(src, dst, x + nd, curs, recs);
        node_sort_kernel<<<NB, 512, 0, stream>>>(offs, recs, bflag, node_offs);
        gather_bf16_kernel<<<(N_NODES + 7) / 8, 512, 0, stream>>>(
            x, h16, offs, node_offs, bflag, recs, out);
    } else {
        const int total = nd + N_EDGES;
        init_out_kernel<<<(total + 255) / 256, 256, 0, stream>>>(x, out, nd, total);
        long long threads = (long long)N_EDGES * 64;
        edge_scatter_kernel<<<(int)((threads + 255) / 256), 256, 0, stream>>>(
            x, x + nd, src, dst, out);
    }
}